// Round 2
// baseline (2167.058 us; speedup 1.0000x reference)
//
#include <hip/hip_runtime.h>
#include <cmath>

// ---------------- problem constants ----------------
constexpr int B_  = 2;
constexpr int C_  = 256;   // NDIM
constexpr int T_  = 512;
constexpr int F_  = 64;
constexpr int N_  = B_ * F_;     // 128 sequences
constexpr int H_  = 8;
constexpr int DH  = 32;          // head dim
constexpr int FF  = 1024;        // R*NDIM
constexpr int WLEN = 128;
constexpr int M_  = N_ * T_;     // 65536 rows
constexpr long long NTC = (long long)N_ * T_ * C_;  // 16777216 elements

// ---------------- transpose in: x (B,C,T,F) -> xs (N=B*F, T, C) ----------------
__global__ __launch_bounds__(256) void k_transpose_in(const float* __restrict__ x,
                                                      float* __restrict__ xs) {
    __shared__ float tile[32][33];
    const int bz = blockIdx.z;            // b*T + t
    const int b = bz >> 9, t = bz & 511;
    const int c0 = blockIdx.x * 32, f0 = blockIdx.y * 32;
    const int tx = threadIdx.x, ty = threadIdx.y;   // 32 x 8
#pragma unroll
    for (int i = 0; i < 4; ++i) {
        int c = c0 + ty + i * 8;
        tile[ty + i * 8][tx] = x[(((size_t)(b * C_ + c)) * T_ + t) * F_ + f0 + tx];
    }
    __syncthreads();
#pragma unroll
    for (int i = 0; i < 4; ++i) {
        int f = f0 + ty + i * 8;
        xs[(((size_t)(b * F_ + f)) * T_ + t) * C_ + c0 + tx] = tile[tx][ty + i * 8];
    }
}

// ---------------- transpose out: tmp (N,T,C) -> out (B,C,T,F) ----------------
__global__ __launch_bounds__(256) void k_transpose_out(const float* __restrict__ tmp,
                                                       float* __restrict__ out) {
    __shared__ float tile[32][33];
    const int bz = blockIdx.z;
    const int b = bz >> 9, t = bz & 511;
    const int c0 = blockIdx.x * 32, f0 = blockIdx.y * 32;
    const int tx = threadIdx.x, ty = threadIdx.y;
#pragma unroll
    for (int i = 0; i < 4; ++i) {
        int f = f0 + ty + i * 8;
        tile[ty + i * 8][tx] = tmp[(((size_t)(b * F_ + f)) * T_ + t) * C_ + c0 + tx];
    }
    __syncthreads();
#pragma unroll
    for (int i = 0; i < 4; ++i) {
        int c = c0 + ty + i * 8;
        out[(((size_t)(b * C_ + c)) * T_ + t) * F_ + f0 + tx] = tile[tx][ty + i * 8];
    }
}

// ---------------- GEMM: out[m][n] = sum_k A[m][k]*W[n][k] + bias[n] (+epilogue) --------
enum { EPI_NONE = 0, EPI_RES = 1, EPI_GELU = 2 };

__device__ __forceinline__ float gelu_f(float v) {
    return 0.5f * v * (1.0f + erff(v * 0.70710678118654752f));
}

template <int EPI>
__global__ __launch_bounds__(256) void k_gemm_nt(const float* __restrict__ A,
                                                 const float* __restrict__ W,
                                                 const float* __restrict__ bias,
                                                 const float* __restrict__ resid,
                                                 float* __restrict__ out,
                                                 int Nout, int K) {
    // BM=BN=64, BK=32. 256 threads, 4x4 micro-tile each.
    __shared__ float As[32][68];  // k-major, padded rows
    __shared__ float Bs[32][68];
    const int n0 = blockIdx.x * 64;
    const int m0 = blockIdx.y * 64;
    const int tid = threadIdx.x;
    const int tx = tid & 15, ty = tid >> 4;

    float acc[4][4] = {{0.f}};

    for (int k0 = 0; k0 < K; k0 += 32) {
#pragma unroll
        for (int i = 0; i < 2; ++i) {
            int idx = tid + i * 256;            // 0..511
            int row = idx >> 3;                 // 0..63
            int kc = (idx & 7) * 4;             // 0..28
            float4 av = *(const float4*)&A[(size_t)(m0 + row) * K + k0 + kc];
            As[kc + 0][row] = av.x; As[kc + 1][row] = av.y;
            As[kc + 2][row] = av.z; As[kc + 3][row] = av.w;
            float4 wv = *(const float4*)&W[(size_t)(n0 + row) * K + k0 + kc];
            Bs[kc + 0][row] = wv.x; Bs[kc + 1][row] = wv.y;
            Bs[kc + 2][row] = wv.z; Bs[kc + 3][row] = wv.w;
        }
        __syncthreads();
#pragma unroll
        for (int k = 0; k < 32; ++k) {
            float4 a = *(const float4*)&As[k][ty * 4];
            float4 b = *(const float4*)&Bs[k][tx * 4];
            acc[0][0] += a.x * b.x; acc[0][1] += a.x * b.y;
            acc[0][2] += a.x * b.z; acc[0][3] += a.x * b.w;
            acc[1][0] += a.y * b.x; acc[1][1] += a.y * b.y;
            acc[1][2] += a.y * b.z; acc[1][3] += a.y * b.w;
            acc[2][0] += a.z * b.x; acc[2][1] += a.z * b.y;
            acc[2][2] += a.z * b.z; acc[2][3] += a.z * b.w;
            acc[3][0] += a.w * b.x; acc[3][1] += a.w * b.y;
            acc[3][2] += a.w * b.z; acc[3][3] += a.w * b.w;
        }
        __syncthreads();
    }

    float4 bv = *(const float4*)&bias[n0 + tx * 4];
#pragma unroll
    for (int r = 0; r < 4; ++r) {
        int row = m0 + ty * 4 + r;
        float4 o;
        o.x = acc[r][0] + bv.x; o.y = acc[r][1] + bv.y;
        o.z = acc[r][2] + bv.z; o.w = acc[r][3] + bv.w;
        if (EPI == EPI_RES) {
            float4 rv = *(const float4*)&resid[(size_t)row * Nout + n0 + tx * 4];
            o.x += rv.x; o.y += rv.y; o.z += rv.z; o.w += rv.w;
        }
        if (EPI == EPI_GELU) {
            o.x = gelu_f(o.x); o.y = gelu_f(o.y);
            o.z = gelu_f(o.z); o.w = gelu_f(o.w);
        }
        *(float4*)&out[(size_t)row * Nout + n0 + tx * 4] = o;
    }
}

// ---------------- windowed causal attention ----------------
// grid (T/64, Ng*H), block 256. 4 lanes per query row (8 dims each of Dh=32).
// qkv is group-local (Ng sequences); ctx is group-local pointer with same layout.
__global__ __launch_bounds__(256) void k_attn(const float* __restrict__ qkv,
                                              float* __restrict__ ctx) {
    __shared__ float Ks[192 * 32];
    __shared__ float Vs[192 * 32];
    const int qt = blockIdx.x;
    const int nh = blockIdx.y;
    const int n = nh >> 3, h = nh & 7;       // group-local sequence
    const int q0 = qt * 64;
    const int jlo = (q0 >= WLEN - 1) ? (q0 - (WLEN - 1)) : 0;
    const int nrows = q0 + 64 - jlo;   // <= 191
    const int tid = threadIdx.x;
    const size_t base = (size_t)n * T_ * (3 * C_);

    for (int idx = tid; idx < nrows * 8; idx += 256) {
        int rj = idx >> 3, dp = (idx & 7) * 4;
        size_t g = base + (size_t)(jlo + rj) * (3 * C_) + h * DH + dp;
        *(float4*)&Ks[rj * 32 + dp] = *(const float4*)&qkv[g + C_];
        *(float4*)&Vs[rj * 32 + dp] = *(const float4*)&qkv[g + 2 * C_];
    }
    __syncthreads();

    const int i = q0 + (tid >> 2);
    const int g4 = tid & 3;
    float qr[8];
    {
        const float* qp = &qkv[base + (size_t)i * (3 * C_) + h * DH + g4 * 8];
        float4 a = *(const float4*)qp;
        float4 b = *(const float4*)(qp + 4);
        qr[0] = a.x; qr[1] = a.y; qr[2] = a.z; qr[3] = a.w;
        qr[4] = b.x; qr[5] = b.y; qr[6] = b.z; qr[7] = b.w;
    }

    float m = -3.0e38f, l = 0.0f;
    float acc[8] = {0.f, 0.f, 0.f, 0.f, 0.f, 0.f, 0.f, 0.f};
    const int jhiEx = q0 + 64;
    for (int j = jlo; j < jhiEx; ++j) {
        int rj = j - jlo;
        const float* kp = &Ks[rj * 32 + g4 * 8];
        float4 k0 = *(const float4*)kp;
        float4 k1 = *(const float4*)(kp + 4);
        float s = qr[0] * k0.x + qr[1] * k0.y + qr[2] * k0.z + qr[3] * k0.w +
                  qr[4] * k1.x + qr[5] * k1.y + qr[6] * k1.z + qr[7] * k1.w;
        s += __shfl_xor(s, 1);
        s += __shfl_xor(s, 2);
        s *= 0.17677669529663687f;   // 1/sqrt(32)
        if (j <= i && j > i - WLEN) {
            if (s > m) {
                float corr = __expf(m - s);
                l *= corr;
#pragma unroll
                for (int d = 0; d < 8; ++d) acc[d] *= corr;
                m = s;
            }
            float p = __expf(s - m);
            l += p;
            const float* vp = &Vs[rj * 32 + g4 * 8];
            float4 v0 = *(const float4*)vp;
            float4 v1 = *(const float4*)(vp + 4);
            acc[0] += p * v0.x; acc[1] += p * v0.y;
            acc[2] += p * v0.z; acc[3] += p * v0.w;
            acc[4] += p * v1.x; acc[5] += p * v1.y;
            acc[6] += p * v1.z; acc[7] += p * v1.w;
        }
    }
    float inv = 1.0f / l;
    float* op = &ctx[((size_t)n * T_ + i) * C_ + h * DH + g4 * 8];
    float4 o0, o1;
    o0.x = acc[0] * inv; o0.y = acc[1] * inv; o0.z = acc[2] * inv; o0.w = acc[3] * inv;
    o1.x = acc[4] * inv; o1.y = acc[5] * inv; o1.z = acc[6] * inv; o1.w = acc[7] * inv;
    *(float4*)op = o0;
    *((float4*)op + 1) = o1;
}

// ---------------- LayerNorm over last dim C=256; one wave per row ----------------
__global__ __launch_bounds__(256) void k_ln(const float* __restrict__ in,
                                            const float* __restrict__ g,
                                            const float* __restrict__ b,
                                            float* __restrict__ out) {
    const int row = blockIdx.x * 4 + (threadIdx.x >> 6);
    const int lane = threadIdx.x & 63;
    const float4 v = *(const float4*)&in[(size_t)row * C_ + lane * 4];
    float s = v.x + v.y + v.z + v.w;
    float sq = v.x * v.x + v.y * v.y + v.z * v.z + v.w * v.w;
#pragma unroll
    for (int off = 1; off < 64; off <<= 1) {
        s += __shfl_xor(s, off);
        sq += __shfl_xor(sq, off);
    }
    float mu = s * (1.0f / C_);
    float var = sq * (1.0f / C_) - mu * mu;
    if (var < 0.f) var = 0.f;
    float rstd = rsqrtf(var + 1e-5f);
    float4 gv = *(const float4*)&g[lane * 4];
    float4 bv = *(const float4*)&b[lane * 4];
    float4 o;
    o.x = (v.x - mu) * rstd * gv.x + bv.x;
    o.y = (v.y - mu) * rstd * gv.y + bv.y;
    o.z = (v.z - mu) * rstd * gv.z + bv.z;
    o.w = (v.w - mu) * rstd * gv.w + bv.w;
    *(float4*)&out[(size_t)row * C_ + lane * 4] = o;
}

// ---------------- launch ----------------
extern "C" void kernel_launch(void* const* d_in, const int* in_sizes, int n_in,
                              void* d_out, int out_size, void* d_ws, size_t ws_size,
                              hipStream_t stream) {
    (void)in_sizes; (void)n_in; (void)out_size;
    const float* x     = (const float*)d_in[0];
    const float* in_w  = (const float*)d_in[1];
    const float* in_b  = (const float*)d_in[2];
    const float* out_w = (const float*)d_in[3];
    const float* out_b = (const float*)d_in[4];
    const float* ln1g  = (const float*)d_in[5];
    const float* ln1b  = (const float*)d_in[6];
    const float* w1    = (const float*)d_in[7];
    const float* b1    = (const float*)d_in[8];
    const float* w2    = (const float*)d_in[9];
    const float* b2    = (const float*)d_in[10];
    const float* ln2g  = (const float*)d_in[11];
    const float* ln2b  = (const float*)d_in[12];
    float* out = (float*)d_out;
    float* ws  = (float*)d_ws;

    // Workspace regions (floats):
    //   A  = [0,    NTC)  : xs (until out-proj), then nrm (LN1 output)
    //   Br = [NTC, 2NTC)  : qkv_g per group, then res1, then tmp2 (LN2 output)
    //   Cr = [2NTC, ...)  : h_g per group (NTC floats at G=4, NTC/2 at G=8)
    // ctx and res2 live in d_out (each exactly out_size floats, dead until
    // overwritten later in the same graph).
    // Peak ws: G=4 -> 3*NTC floats (192 MiB); G=8 -> 2.5*NTC (160 MiB).
    const int G = (ws_size >= (size_t)3 * NTC * sizeof(float)) ? 4 : 8;
    const int Ng = N_ / G;                 // sequences per group
    const long long Mg = (long long)Ng * T_;  // rows per group

    float* xs   = ws;                       // region A
    float* nrm  = ws;                       // region A (xs dead by then)
    float* qkvg = ws + NTC;                 // region B
    float* res1 = ws + NTC;                 // region B (qkv_g dead)
    float* tmp2 = ws + NTC;                 // region B (res1 dead)
    float* hbuf = ws + 2 * NTC;             // region C
    float* ctx  = out;                      // d_out as scratch
    float* res2 = out;                      // d_out as scratch (ctx dead)

    dim3 tb(32, 8);
    k_transpose_in<<<dim3(C_ / 32, F_ / 32, B_ * T_), tb, 0, stream>>>(x, xs);

    // QKV projection + attention, per sequence-group (qkv_g reused)
    for (int g = 0; g < G; ++g) {
        const float* xs_g = xs + (size_t)g * Mg * C_;
        k_gemm_nt<EPI_NONE><<<dim3(3 * C_ / 64, Mg / 64), 256, 0, stream>>>(
            xs_g, in_w, in_b, nullptr, qkvg, 3 * C_, C_);
        k_attn<<<dim3(T_ / 64, Ng * H_), 256, 0, stream>>>(
            qkvg, ctx + (size_t)g * Mg * C_);
    }

    // out projection + residual(xs)  (full M)
    k_gemm_nt<EPI_RES><<<dim3(C_ / 64, M_ / 64), 256, 0, stream>>>(
        ctx, out_w, out_b, xs, res1, C_, C_);

    // LN1 (full M): res1 -> nrm (overwrites xs region; xs dead now)
    k_ln<<<M_ / 4, 256, 0, stream>>>(res1, ln1g, ln1b, nrm);

    // FFN per row-group (h_g reused); res2 accumulates in d_out
    for (int g = 0; g < G; ++g) {
        const float* nrm_g = nrm + (size_t)g * Mg * C_;
        k_gemm_nt<EPI_GELU><<<dim3(FF / 64, Mg / 64), 256, 0, stream>>>(
            nrm_g, w1, b1, nullptr, hbuf, FF, C_);
        k_gemm_nt<EPI_RES><<<dim3(C_ / 64, Mg / 64), 256, 0, stream>>>(
            hbuf, w2, b2, nrm_g, res2 + (size_t)g * Mg * C_, C_, FF);
    }

    // LN2 (full M): res2(d_out) -> tmp2 (region B)
    k_ln<<<M_ / 4, 256, 0, stream>>>(res2, ln2g, ln2b, tmp2);

    // back to (B,C,T,F)
    k_transpose_out<<<dim3(C_ / 32, F_ / 32, B_ * T_), tb, 0, stream>>>(tmp2, out);
}

// Round 5
// 1055.873 us; speedup vs baseline: 2.0524x; 2.0524x over previous
//
#include <hip/hip_runtime.h>
#include <cmath>

// ---------------- problem constants ----------------
constexpr int B_  = 2;
constexpr int C_  = 256;   // NDIM
constexpr int T_  = 512;
constexpr int F_  = 64;
constexpr int N_  = B_ * F_;     // 128 sequences
constexpr int H_  = 8;
constexpr int DH  = 32;          // head dim
constexpr int FF  = 1024;        // R*NDIM
constexpr int WLEN = 128;
constexpr int M_  = N_ * T_;     // 65536 rows
constexpr long long NTC = (long long)N_ * T_ * C_;  // 16777216 elements

typedef _Float16 half8 __attribute__((ext_vector_type(8)));
typedef _Float16 half4v __attribute__((ext_vector_type(4)));
typedef float f32x4 __attribute__((ext_vector_type(4)));

// ---------------- fp32 -> fp16 convert (weights) ----------------
__global__ __launch_bounds__(256) void k_cvt16(const float* __restrict__ in,
                                               _Float16* __restrict__ out, int n4) {
    int i = blockIdx.x * 256 + threadIdx.x;
    if (i < n4) {
        float4 v = ((const float4*)in)[i];
        half4v h = { (_Float16)v.x, (_Float16)v.y, (_Float16)v.z, (_Float16)v.w };
        *(half4v*)&out[(size_t)i * 4] = h;
    }
}

// ---------------- transpose in: x (B,C,T,F) -> xs (N=B*F, T, C) ----------------
__global__ __launch_bounds__(256) void k_transpose_in(const float* __restrict__ x,
                                                      float* __restrict__ xs) {
    __shared__ float tile[32][33];
    const int bz = blockIdx.z;            // b*T + t
    const int b = bz >> 9, t = bz & 511;
    const int c0 = blockIdx.x * 32, f0 = blockIdx.y * 32;
    const int tx = threadIdx.x, ty = threadIdx.y;   // 32 x 8
#pragma unroll
    for (int i = 0; i < 4; ++i) {
        int c = c0 + ty + i * 8;
        tile[ty + i * 8][tx] = x[(((size_t)(b * C_ + c)) * T_ + t) * F_ + f0 + tx];
    }
    __syncthreads();
#pragma unroll
    for (int i = 0; i < 4; ++i) {
        int f = f0 + ty + i * 8;
        xs[(((size_t)(b * F_ + f)) * T_ + t) * C_ + c0 + tx] = tile[tx][ty + i * 8];
    }
}

// ---------------- transpose out: tmp (N,T,C) -> out (B,C,T,F) ----------------
__global__ __launch_bounds__(256) void k_transpose_out(const float* __restrict__ tmp,
                                                       float* __restrict__ out) {
    __shared__ float tile[32][33];
    const int bz = blockIdx.z;
    const int b = bz >> 9, t = bz & 511;
    const int c0 = blockIdx.x * 32, f0 = blockIdx.y * 32;
    const int tx = threadIdx.x, ty = threadIdx.y;
#pragma unroll
    for (int i = 0; i < 4; ++i) {
        int f = f0 + ty + i * 8;
        tile[ty + i * 8][tx] = tmp[(((size_t)(b * F_ + f)) * T_ + t) * C_ + c0 + tx];
    }
    __syncthreads();
#pragma unroll
    for (int i = 0; i < 4; ++i) {
        int c = c0 + ty + i * 8;
        out[(((size_t)(b * C_ + c)) * T_ + t) * F_ + f0 + tx] = tile[tx][ty + i * 8];
    }
}

// ---------------- MFMA GEMM: out[m][n] = sum_k A[m][k]*W[n][k] + bias[n] ----------------
enum { EPI_NONE = 0, EPI_RES = 1, EPI_GELU = 2 };

__device__ __forceinline__ float gelu_f(float v) {
    return 0.5f * v * (1.0f + erff(v * 0.70710678118654752f));
}

// BM=BN=128, BK=32, 256 threads = 4 waves, each wave 64x64 via 4x4 16x16x32 MFMA frags.
// LDS tiles [row][k] with 40-half pitch (80B rows, 16B aligned, 2-way-free b128).
template <int EPI, bool A_F16, bool OUT_F16>
__global__ __launch_bounds__(256) void k_gemm_mfma(const void* __restrict__ Aptr,
                                                   const _Float16* __restrict__ W,
                                                   const float* __restrict__ bias,
                                                   const float* __restrict__ resid,
                                                   void* __restrict__ outp,
                                                   int Nout, int K) {
    __shared__ _Float16 As[128][40];
    __shared__ _Float16 Bs[128][40];
    const int n0 = blockIdx.x * 128;
    const int m0 = blockIdx.y * 128;
    const int tid  = threadIdx.x;
    const int lane = tid & 63;
    const int wid  = tid >> 6;
    const int wm = wid >> 1, wn = wid & 1;
    const int srow = tid >> 1;           // 0..127
    const int skh  = (tid & 1) * 16;     // 0 or 16

    f32x4 acc[4][4] = {};

    for (int k0 = 0; k0 < K; k0 += 32) {
        // ---- stage A tile (128 x 32 halves) ----
        if (A_F16) {
            const _Float16* ap = (const _Float16*)Aptr + (size_t)(m0 + srow) * K + k0 + skh;
            half8 a0 = ((const half8*)ap)[0];
            half8 a1 = ((const half8*)ap)[1];
            *(half8*)&As[srow][skh]     = a0;
            *(half8*)&As[srow][skh + 8] = a1;
        } else {
            const float* ap = (const float*)Aptr + (size_t)(m0 + srow) * K + k0 + skh;
            float4 v0 = ((const float4*)ap)[0];
            float4 v1 = ((const float4*)ap)[1];
            float4 v2 = ((const float4*)ap)[2];
            float4 v3 = ((const float4*)ap)[3];
            half8 a0 = { (_Float16)v0.x, (_Float16)v0.y, (_Float16)v0.z, (_Float16)v0.w,
                         (_Float16)v1.x, (_Float16)v1.y, (_Float16)v1.z, (_Float16)v1.w };
            half8 a1 = { (_Float16)v2.x, (_Float16)v2.y, (_Float16)v2.z, (_Float16)v2.w,
                         (_Float16)v3.x, (_Float16)v3.y, (_Float16)v3.z, (_Float16)v3.w };
            *(half8*)&As[srow][skh]     = a0;
            *(half8*)&As[srow][skh + 8] = a1;
        }
        // ---- stage B tile (weights, fp16) ----
        {
            const _Float16* bp = W + (size_t)(n0 + srow) * K + k0 + skh;
            half8 b0 = ((const half8*)bp)[0];
            half8 b1 = ((const half8*)bp)[1];
            *(half8*)&Bs[srow][skh]     = b0;
            *(half8*)&Bs[srow][skh + 8] = b1;
        }
        __syncthreads();

        half8 af[4], bf[4];
#pragma unroll
        for (int mi = 0; mi < 4; ++mi)
            af[mi] = *(const half8*)&As[wm * 64 + mi * 16 + (lane & 15)][(lane >> 4) * 8];
#pragma unroll
        for (int ni = 0; ni < 4; ++ni)
            bf[ni] = *(const half8*)&Bs[wn * 64 + ni * 16 + (lane & 15)][(lane >> 4) * 8];
#pragma unroll
        for (int mi = 0; mi < 4; ++mi)
#pragma unroll
            for (int ni = 0; ni < 4; ++ni)
                acc[mi][ni] = __builtin_amdgcn_mfma_f32_16x16x32_f16(
                    af[mi], bf[ni], acc[mi][ni], 0, 0, 0);
        __syncthreads();
    }

    // ---- epilogue: C/D frag layout col=lane&15, row=(lane>>4)*4+r ----
    const int colb = n0 + wn * 64 + (lane & 15);
    const int rowb = m0 + wm * 64 + ((lane >> 4) << 2);
#pragma unroll
    for (int ni = 0; ni < 4; ++ni) {
        const int col = colb + ni * 16;
        const float bv = bias[col];
#pragma unroll
        for (int mi = 0; mi < 4; ++mi) {
#pragma unroll
            for (int r = 0; r < 4; ++r) {
                const int row = rowb + mi * 16 + r;
                float v = acc[mi][ni][r] + bv;
                if (EPI == EPI_RES)  v += resid[(size_t)row * Nout + col];
                if (EPI == EPI_GELU) v = gelu_f(v);
                if (OUT_F16) ((_Float16*)outp)[(size_t)row * Nout + col] = (_Float16)v;
                else         ((float*)outp)[(size_t)row * Nout + col] = v;
            }
        }
    }
}

// ---------------- windowed causal attention (fp16 qkv in, fp32 ctx out) ----------------
// grid (T/64, Ng*H), block 256. 4 lanes per query row (8 dims each of Dh=32).
__global__ __launch_bounds__(256) void k_attn(const _Float16* __restrict__ qkv,
                                              float* __restrict__ ctx) {
    __shared__ float Ks[192 * 32];
    __shared__ float Vs[192 * 32];
    const int qt = blockIdx.x;
    const int nh = blockIdx.y;
    const int n = nh >> 3, h = nh & 7;       // group-local sequence
    const int q0 = qt * 64;
    const int jlo = (q0 >= WLEN - 1) ? (q0 - (WLEN - 1)) : 0;
    const int nrows = q0 + 64 - jlo;   // <= 191
    const int tid = threadIdx.x;
    const size_t base = (size_t)n * T_ * (3 * C_);

    for (int idx = tid; idx < nrows * 4; idx += 256) {
        int rj = idx >> 2, dp = (idx & 3) * 8;
        size_t g = base + (size_t)(jlo + rj) * (3 * C_) + h * DH + dp;
        half8 kk = *(const half8*)&qkv[g + C_];
        half8 vv = *(const half8*)&qkv[g + 2 * C_];
#pragma unroll
        for (int j = 0; j < 8; ++j) {
            Ks[rj * 32 + dp + j] = (float)kk[j];
            Vs[rj * 32 + dp + j] = (float)vv[j];
        }
    }
    __syncthreads();

    const int i = q0 + (tid >> 2);
    const int g4 = tid & 3;
    float qr[8];
    {
        half8 qv = *(const half8*)&qkv[base + (size_t)i * (3 * C_) + h * DH + g4 * 8];
#pragma unroll
        for (int j = 0; j < 8; ++j) qr[j] = (float)qv[j];
    }

    float m = -3.0e38f, l = 0.0f;
    float acc[8] = {0.f, 0.f, 0.f, 0.f, 0.f, 0.f, 0.f, 0.f};
    const int jhiEx = q0 + 64;
    for (int j = jlo; j < jhiEx; ++j) {
        int rj = j - jlo;
        const float* kp = &Ks[rj * 32 + g4 * 8];
        float4 k0 = *(const float4*)kp;
        float4 k1 = *(const float4*)(kp + 4);
        float s = qr[0] * k0.x + qr[1] * k0.y + qr[2] * k0.z + qr[3] * k0.w +
                  qr[4] * k1.x + qr[5] * k1.y + qr[6] * k1.z + qr[7] * k1.w;
        s += __shfl_xor(s, 1);
        s += __shfl_xor(s, 2);
        s *= 0.17677669529663687f;   // 1/sqrt(32)
        if (j <= i && j > i - WLEN) {
            if (s > m) {
                float corr = __expf(m - s);
                l *= corr;
#pragma unroll
                for (int d = 0; d < 8; ++d) acc[d] *= corr;
                m = s;
            }
            float p = __expf(s - m);
            l += p;
            const float* vp = &Vs[rj * 32 + g4 * 8];
            float4 v0 = *(const float4*)vp;
            float4 v1 = *(const float4*)(vp + 4);
            acc[0] += p * v0.x; acc[1] += p * v0.y;
            acc[2] += p * v0.z; acc[3] += p * v0.w;
            acc[4] += p * v1.x; acc[5] += p * v1.y;
            acc[6] += p * v1.z; acc[7] += p * v1.w;
        }
    }
    float inv = 1.0f / l;
    float* op = &ctx[((size_t)n * T_ + i) * C_ + h * DH + g4 * 8];
    float4 o0, o1;
    o0.x = acc[0] * inv; o0.y = acc[1] * inv; o0.z = acc[2] * inv; o0.w = acc[3] * inv;
    o1.x = acc[4] * inv; o1.y = acc[5] * inv; o1.z = acc[6] * inv; o1.w = acc[7] * inv;
    *(float4*)op = o0;
    *((float4*)op + 1) = o1;
}

// ---------------- LayerNorm over last dim C=256; one wave per row ----------------
__global__ __launch_bounds__(256) void k_ln(const float* __restrict__ in,
                                            const float* __restrict__ g,
                                            const float* __restrict__ b,
                                            float* __restrict__ out) {
    const int row = blockIdx.x * 4 + (threadIdx.x >> 6);
    const int lane = threadIdx.x & 63;
    const float4 v = *(const float4*)&in[(size_t)row * C_ + lane * 4];
    float s = v.x + v.y + v.z + v.w;
    float sq = v.x * v.x + v.y * v.y + v.z * v.z + v.w * v.w;
#pragma unroll
    for (int off = 1; off < 64; off <<= 1) {
        s += __shfl_xor(s, off);
        sq += __shfl_xor(sq, off);
    }
    float mu = s * (1.0f / C_);
    float var = sq * (1.0f / C_) - mu * mu;
    if (var < 0.f) var = 0.f;
    float rstd = rsqrtf(var + 1e-5f);
    float4 gv = *(const float4*)&g[lane * 4];
    float4 bv = *(const float4*)&b[lane * 4];
    float4 o;
    o.x = (v.x - mu) * rstd * gv.x + bv.x;
    o.y = (v.y - mu) * rstd * gv.y + bv.y;
    o.z = (v.z - mu) * rstd * gv.z + bv.z;
    o.w = (v.w - mu) * rstd * gv.w + bv.w;
    *(float4*)&out[(size_t)row * C_ + lane * 4] = o;
}

// ---------------- launch ----------------
extern "C" void kernel_launch(void* const* d_in, const int* in_sizes, int n_in,
                              void* d_out, int out_size, void* d_ws, size_t ws_size,
                              hipStream_t stream) {
    (void)in_sizes; (void)n_in; (void)out_size;
    const float* x     = (const float*)d_in[0];
    const float* in_w  = (const float*)d_in[1];
    const float* in_b  = (const float*)d_in[2];
    const float* out_w = (const float*)d_in[3];
    const float* out_b = (const float*)d_in[4];
    const float* ln1g  = (const float*)d_in[5];
    const float* ln1b  = (const float*)d_in[6];
    const float* w1    = (const float*)d_in[7];
    const float* b1    = (const float*)d_in[8];
    const float* w2    = (const float*)d_in[9];
    const float* b2    = (const float*)d_in[10];
    const float* ln2g  = (const float*)d_in[11];
    const float* ln2b  = (const float*)d_in[12];
    float* out = (float*)d_out;
    float* ws  = (float*)d_ws;

    // Workspace (floats):
    //   A  = [0, NTC)       : xs, then nrm (after LN1)
    //   B  = [NTC, 2NTC)    : qkv16 (fp16, Mg*768 halves) -> res1 -> tmp2
    //   C  = [2NTC, ...)    : h16 (fp16, Mg*1024 halves = Mg*512 floats), then W16 tail
    // ctx / res2 live in d_out. Peak: G=4 -> ~170 MiB, G=8 -> ~153 MiB.
    const int G = (ws_size >= (size_t)3 * NTC * sizeof(float)) ? 4 : 8;
    const int Ng = N_ / G;
    const long long Mg = (long long)Ng * T_;

    float* xs   = ws;
    float* nrm  = ws;
    _Float16* qkv16 = (_Float16*)(ws + NTC);
    float* res1 = ws + NTC;
    float* tmp2 = ws + NTC;
    _Float16* h16 = (_Float16*)(ws + 2 * NTC);
    float* wtail = ws + 2 * NTC + (size_t)Mg * 512;
    _Float16* w16_in  = (_Float16*)wtail;           // 196608
    _Float16* w16_out = w16_in + 196608;            // 65536
    _Float16* w16_1   = w16_out + 65536;            // 262144
    _Float16* w16_2   = w16_1 + 262144;             // 262144
    float* ctx  = out;
    float* res2 = out;

    // weight conversion
    k_cvt16<<<192, 256, 0, stream>>>(in_w,  w16_in,  196608 / 4);
    k_cvt16<<<64,  256, 0, stream>>>(out_w, w16_out, 65536 / 4);
    k_cvt16<<<256, 256, 0, stream>>>(w1,    w16_1,   262144 / 4);
    k_cvt16<<<256, 256, 0, stream>>>(w2,    w16_2,   262144 / 4);

    dim3 tb(32, 8);
    k_transpose_in<<<dim3(C_ / 32, F_ / 32, B_ * T_), tb, 0, stream>>>(x, xs);

    // QKV projection + attention, per sequence-group
    for (int g = 0; g < G; ++g) {
        const float* xs_g = xs + (size_t)g * Mg * C_;
        k_gemm_mfma<EPI_NONE, false, true><<<dim3(768 / 128, Mg / 128), 256, 0, stream>>>(
            xs_g, w16_in, in_b, nullptr, qkv16, 3 * C_, C_);
        k_attn<<<dim3(T_ / 64, Ng * H_), 256, 0, stream>>>(
            qkv16, ctx + (size_t)g * Mg * C_);
    }

    // out projection + residual(xs), full M
    k_gemm_mfma<EPI_RES, false, false><<<dim3(C_ / 128, M_ / 128), 256, 0, stream>>>(
        ctx, w16_out, out_b, xs, res1, C_, C_);

    // LN1: res1 -> nrm
    k_ln<<<M_ / 4, 256, 0, stream>>>(res1, ln1g, ln1b, nrm);

    // FFN per row-group
    for (int g = 0; g < G; ++g) {
        const float* nrm_g = nrm + (size_t)g * Mg * C_;
        k_gemm_mfma<EPI_GELU, false, true><<<dim3(FF / 128, Mg / 128), 256, 0, stream>>>(
            nrm_g, w16_1, b1, nullptr, h16, FF, C_);
        k_gemm_mfma<EPI_RES, true, false><<<dim3(C_ / 128, Mg / 128), 256, 0, stream>>>(
            h16, w16_2, b2, nrm_g, res2 + (size_t)g * Mg * C_, C_, FF);
    }

    // LN2: res2(d_out) -> tmp2
    k_ln<<<M_ / 4, 256, 0, stream>>>(res2, ln2g, ln2b, tmp2);

    // back to (B,C,T,F)
    k_transpose_out<<<dim3(C_ / 32, F_ / 32, B_ * T_), tb, 0, stream>>>(tmp2, out);
}

// Round 6
// 708.856 us; speedup vs baseline: 3.0571x; 1.4895x over previous
//
#include <hip/hip_runtime.h>
#include <cmath>

// ---------------- problem constants ----------------
constexpr int B_  = 2;
constexpr int C_  = 256;   // NDIM
constexpr int T_  = 512;
constexpr int F_  = 64;
constexpr int N_  = B_ * F_;     // 128 sequences
constexpr int H_  = 8;
constexpr int DH  = 32;          // head dim
constexpr int FF  = 1024;        // R*NDIM
constexpr int WLEN = 128;
constexpr int M_  = N_ * T_;     // 65536 rows
constexpr long long NTC = (long long)N_ * T_ * C_;  // 16777216 elements

typedef _Float16 half8 __attribute__((ext_vector_type(8)));
typedef _Float16 half4v __attribute__((ext_vector_type(4)));
typedef float f32x4 __attribute__((ext_vector_type(4)));

// ---------------- fp32 -> fp16 convert (weights) ----------------
__global__ __launch_bounds__(256) void k_cvt16(const float* __restrict__ in,
                                               _Float16* __restrict__ out, int n4) {
    int i = blockIdx.x * 256 + threadIdx.x;
    if (i < n4) {
        float4 v = ((const float4*)in)[i];
        half4v h = { (_Float16)v.x, (_Float16)v.y, (_Float16)v.z, (_Float16)v.w };
        *(half4v*)&out[(size_t)i * 4] = h;
    }
}

// ---------------- transpose in: x (B,C,T,F) -> xs (N=B*F, T, C) ----------------
__global__ __launch_bounds__(256) void k_transpose_in(const float* __restrict__ x,
                                                      float* __restrict__ xs) {
    __shared__ float tile[32][33];
    const int bz = blockIdx.z;            // b*T + t
    const int b = bz >> 9, t = bz & 511;
    const int c0 = blockIdx.x * 32, f0 = blockIdx.y * 32;
    const int tx = threadIdx.x, ty = threadIdx.y;   // 32 x 8
#pragma unroll
    for (int i = 0; i < 4; ++i) {
        int c = c0 + ty + i * 8;
        tile[ty + i * 8][tx] = x[(((size_t)(b * C_ + c)) * T_ + t) * F_ + f0 + tx];
    }
    __syncthreads();
#pragma unroll
    for (int i = 0; i < 4; ++i) {
        int f = f0 + ty + i * 8;
        xs[(((size_t)(b * F_ + f)) * T_ + t) * C_ + c0 + tx] = tile[tx][ty + i * 8];
    }
}

// ---------------- transpose out: tmp (N,T,C) -> out (B,C,T,F) ----------------
__global__ __launch_bounds__(256) void k_transpose_out(const float* __restrict__ tmp,
                                                       float* __restrict__ out) {
    __shared__ float tile[32][33];
    const int bz = blockIdx.z;
    const int b = bz >> 9, t = bz & 511;
    const int c0 = blockIdx.x * 32, f0 = blockIdx.y * 32;
    const int tx = threadIdx.x, ty = threadIdx.y;
#pragma unroll
    for (int i = 0; i < 4; ++i) {
        int f = f0 + ty + i * 8;
        tile[ty + i * 8][tx] = tmp[(((size_t)(b * F_ + f)) * T_ + t) * C_ + c0 + tx];
    }
    __syncthreads();
#pragma unroll
    for (int i = 0; i < 4; ++i) {
        int c = c0 + ty + i * 8;
        out[(((size_t)(b * C_ + c)) * T_ + t) * F_ + f0 + tx] = tile[tx][ty + i * 8];
    }
}

// ---------------- MFMA GEMM: out[m][n] = sum_k A[m][k]*W[n][k] + bias[n] ----------------
enum { EPI_NONE = 0, EPI_RES = 1, EPI_GELU = 2 };

__device__ __forceinline__ float gelu_f(float v) {
    return 0.5f * v * (1.0f + erff(v * 0.70710678118654752f));
}

// BM=BN=128, BK=32, 256 threads = 4 waves, each wave 64x64 via 4x4 16x16x32 MFMA frags.
template <int EPI, bool A_F16, bool OUT_F16>
__global__ __launch_bounds__(256) void k_gemm_mfma(const void* __restrict__ Aptr,
                                                   const _Float16* __restrict__ W,
                                                   const float* __restrict__ bias,
                                                   const float* __restrict__ resid,
                                                   void* __restrict__ outp,
                                                   int Nout, int K) {
    __shared__ _Float16 As[128][40];
    __shared__ _Float16 Bs[128][40];
    const int n0 = blockIdx.x * 128;
    const int m0 = blockIdx.y * 128;
    const int tid  = threadIdx.x;
    const int lane = tid & 63;
    const int wid  = tid >> 6;
    const int wm = wid >> 1, wn = wid & 1;
    const int srow = tid >> 1;           // 0..127
    const int skh  = (tid & 1) * 16;     // 0 or 16

    f32x4 acc[4][4] = {};

    for (int k0 = 0; k0 < K; k0 += 32) {
        if (A_F16) {
            const _Float16* ap = (const _Float16*)Aptr + (size_t)(m0 + srow) * K + k0 + skh;
            half8 a0 = ((const half8*)ap)[0];
            half8 a1 = ((const half8*)ap)[1];
            *(half8*)&As[srow][skh]     = a0;
            *(half8*)&As[srow][skh + 8] = a1;
        } else {
            const float* ap = (const float*)Aptr + (size_t)(m0 + srow) * K + k0 + skh;
            float4 v0 = ((const float4*)ap)[0];
            float4 v1 = ((const float4*)ap)[1];
            float4 v2 = ((const float4*)ap)[2];
            float4 v3 = ((const float4*)ap)[3];
            half8 a0 = { (_Float16)v0.x, (_Float16)v0.y, (_Float16)v0.z, (_Float16)v0.w,
                         (_Float16)v1.x, (_Float16)v1.y, (_Float16)v1.z, (_Float16)v1.w };
            half8 a1 = { (_Float16)v2.x, (_Float16)v2.y, (_Float16)v2.z, (_Float16)v2.w,
                         (_Float16)v3.x, (_Float16)v3.y, (_Float16)v3.z, (_Float16)v3.w };
            *(half8*)&As[srow][skh]     = a0;
            *(half8*)&As[srow][skh + 8] = a1;
        }
        {
            const _Float16* bp = W + (size_t)(n0 + srow) * K + k0 + skh;
            half8 b0 = ((const half8*)bp)[0];
            half8 b1 = ((const half8*)bp)[1];
            *(half8*)&Bs[srow][skh]     = b0;
            *(half8*)&Bs[srow][skh + 8] = b1;
        }
        __syncthreads();

        half8 af[4], bf[4];
#pragma unroll
        for (int mi = 0; mi < 4; ++mi)
            af[mi] = *(const half8*)&As[wm * 64 + mi * 16 + (lane & 15)][(lane >> 4) * 8];
#pragma unroll
        for (int ni = 0; ni < 4; ++ni)
            bf[ni] = *(const half8*)&Bs[wn * 64 + ni * 16 + (lane & 15)][(lane >> 4) * 8];
#pragma unroll
        for (int mi = 0; mi < 4; ++mi)
#pragma unroll
            for (int ni = 0; ni < 4; ++ni)
                acc[mi][ni] = __builtin_amdgcn_mfma_f32_16x16x32_f16(
                    af[mi], bf[ni], acc[mi][ni], 0, 0, 0);
        __syncthreads();
    }

    const int colb = n0 + wn * 64 + (lane & 15);
    const int rowb = m0 + wm * 64 + ((lane >> 4) << 2);
#pragma unroll
    for (int ni = 0; ni < 4; ++ni) {
        const int col = colb + ni * 16;
        const float bv = bias[col];
#pragma unroll
        for (int mi = 0; mi < 4; ++mi) {
#pragma unroll
            for (int r = 0; r < 4; ++r) {
                const int row = rowb + mi * 16 + r;
                float v = acc[mi][ni][r] + bv;
                if (EPI == EPI_RES)  v += resid[(size_t)row * Nout + col];
                if (EPI == EPI_GELU) v = gelu_f(v);
                if (OUT_F16) ((_Float16*)outp)[(size_t)row * Nout + col] = (_Float16)v;
                else         ((float*)outp)[(size_t)row * Nout + col] = v;
            }
        }
    }
}

// ---------------- MFMA windowed causal attention ----------------
// grid (T/64, Ng*H), block 256 = 4 waves. Wave w handles queries q0+w*16..+15.
// QK^T: A=Q-frag (global), B=K-frag (global), 12 j-tiles of 16 keys.
// Softmax wave-parallel over lane&15; P (fp16, unnormalized) -> LDS; PV via MFMA
// with V^T staged in LDS. ctx written fp16.
__global__ __launch_bounds__(256) void k_attn_mfma(const _Float16* __restrict__ qkv,
                                                   _Float16* __restrict__ ctx) {
    __shared__ _Float16 Vt[32][200];   // V^T: [dim][key]  (12.8 KB)
    __shared__ _Float16 Pl[64][200];   // P:   [query][key] (25.6 KB)
    const int qt = blockIdx.x;
    const int nh = blockIdx.y;
    const int n = nh >> 3, h = nh & 7;     // group-local sequence
    const int q0 = qt * 64;
    const int jlo = (q0 >= WLEN - 1) ? (q0 - (WLEN - 1)) : 0;
    const int tid = threadIdx.x;
    const int w = tid >> 6;
    const int lane = tid & 63;
    const int g = lane >> 4, c = lane & 15;
    const size_t base = (size_t)n * T_ * (3 * C_);
    const int hq = h * DH;

    // ---- stage V^T (clamp rows past T; masked P makes them harmless) ----
    for (int idx = tid; idx < 192 * 4; idx += 256) {
        int rj = idx >> 2, dp = (idx & 3) * 8;
        int vr = jlo + rj; if (vr > T_ - 1) vr = T_ - 1;
        half8 vv = *(const half8*)&qkv[base + (size_t)vr * (3 * C_) + 2 * C_ + hq + dp];
#pragma unroll
        for (int u = 0; u < 8; ++u) Vt[dp + u][rj] = vv[u];
    }

    // ---- Q fragment: row=c -> query q0+w*16+c, k=(g)*8.. over all 32 dims ----
    half8 qf = *(const half8*)&qkv[base + (size_t)(q0 + w * 16 + c) * (3 * C_) + hq + g * 8];

    // ---- QK^T: 12 key tiles of 16 ----
    f32x4 s[12];
#pragma unroll
    for (int t = 0; t < 12; ++t) {
        int jr = jlo + 16 * t + c; if (jr > T_ - 1) jr = T_ - 1;
        half8 kf = *(const half8*)&qkv[base + (size_t)jr * (3 * C_) + C_ + hq + g * 8];
        f32x4 z = {0.f, 0.f, 0.f, 0.f};
        s[t] = __builtin_amdgcn_mfma_f32_16x16x32_f16(qf, kf, z, 0, 0, 0);
    }

    // ---- masked softmax; lane's queries are i = q0+w*16+4g+r ----
    const float scale = 0.17677669529663687f;   // 1/sqrt(32)
    float invl[4];
#pragma unroll
    for (int r = 0; r < 4; ++r) {
        const int i = q0 + w * 16 + 4 * g + r;
        float m = -3.0e38f;
        float sv[12];
#pragma unroll
        for (int t = 0; t < 12; ++t) {
            int j = jlo + 16 * t + c;
            bool ok = (j <= i) && (j > i - WLEN);
            float v = ok ? s[t][r] * scale : -3.0e38f;
            sv[t] = v;
            m = fmaxf(m, v);
        }
        m = fmaxf(m, __shfl_xor(m, 1));
        m = fmaxf(m, __shfl_xor(m, 2));
        m = fmaxf(m, __shfl_xor(m, 4));
        m = fmaxf(m, __shfl_xor(m, 8));
        float l = 0.f;
#pragma unroll
        for (int t = 0; t < 12; ++t) {
            float p = (sv[t] > -1.0e38f) ? __expf(sv[t] - m) : 0.f;
            l += p;
            Pl[w * 16 + 4 * g + r][16 * t + c] = (_Float16)p;
        }
        l += __shfl_xor(l, 1);
        l += __shfl_xor(l, 2);
        l += __shfl_xor(l, 4);
        l += __shfl_xor(l, 8);
        invl[r] = 1.0f / l;   // lane's query mapping (4g+r) matches PV output rows
    }
    __syncthreads();

    // ---- PV: out[i][d] = sum_j P[i][j] V[j][d]; A=P rows (query=c), B=Vt rows (dim=c) ----
    f32x4 o0 = {0.f, 0.f, 0.f, 0.f}, o1 = {0.f, 0.f, 0.f, 0.f};
#pragma unroll
    for (int ks = 0; ks < 6; ++ks) {
        half8 pa = *(const half8*)&Pl[w * 16 + c][32 * ks + 8 * g];
        half8 b0 = *(const half8*)&Vt[c][32 * ks + 8 * g];
        half8 b1 = *(const half8*)&Vt[c + 16][32 * ks + 8 * g];
        o0 = __builtin_amdgcn_mfma_f32_16x16x32_f16(pa, b0, o0, 0, 0, 0);
        o1 = __builtin_amdgcn_mfma_f32_16x16x32_f16(pa, b1, o1, 0, 0, 0);
    }
#pragma unroll
    for (int r = 0; r < 4; ++r) {
        const int i = q0 + w * 16 + 4 * g + r;
        _Float16* op = &ctx[((size_t)n * T_ + i) * C_ + hq];
        op[c]      = (_Float16)(o0[r] * invl[r]);
        op[c + 16] = (_Float16)(o1[r] * invl[r]);
    }
}

// ---------------- LayerNorm over last dim C=256; one wave per row ----------------
__global__ __launch_bounds__(256) void k_ln(const float* __restrict__ in,
                                            const float* __restrict__ g,
                                            const float* __restrict__ b,
                                            float* __restrict__ out) {
    const int row = blockIdx.x * 4 + (threadIdx.x >> 6);
    const int lane = threadIdx.x & 63;
    const float4 v = *(const float4*)&in[(size_t)row * C_ + lane * 4];
    float s = v.x + v.y + v.z + v.w;
    float sq = v.x * v.x + v.y * v.y + v.z * v.z + v.w * v.w;
#pragma unroll
    for (int off = 1; off < 64; off <<= 1) {
        s += __shfl_xor(s, off);
        sq += __shfl_xor(sq, off);
    }
    float mu = s * (1.0f / C_);
    float var = sq * (1.0f / C_) - mu * mu;
    if (var < 0.f) var = 0.f;
    float rstd = rsqrtf(var + 1e-5f);
    float4 gv = *(const float4*)&g[lane * 4];
    float4 bv = *(const float4*)&b[lane * 4];
    float4 o;
    o.x = (v.x - mu) * rstd * gv.x + bv.x;
    o.y = (v.y - mu) * rstd * gv.y + bv.y;
    o.z = (v.z - mu) * rstd * gv.z + bv.z;
    o.w = (v.w - mu) * rstd * gv.w + bv.w;
    *(float4*)&out[(size_t)row * C_ + lane * 4] = o;
}

// ---------------- launch ----------------
extern "C" void kernel_launch(void* const* d_in, const int* in_sizes, int n_in,
                              void* d_out, int out_size, void* d_ws, size_t ws_size,
                              hipStream_t stream) {
    (void)in_sizes; (void)n_in; (void)out_size;
    const float* x     = (const float*)d_in[0];
    const float* in_w  = (const float*)d_in[1];
    const float* in_b  = (const float*)d_in[2];
    const float* out_w = (const float*)d_in[3];
    const float* out_b = (const float*)d_in[4];
    const float* ln1g  = (const float*)d_in[5];
    const float* ln1b  = (const float*)d_in[6];
    const float* w1    = (const float*)d_in[7];
    const float* b1    = (const float*)d_in[8];
    const float* w2    = (const float*)d_in[9];
    const float* b2    = (const float*)d_in[10];
    const float* ln2g  = (const float*)d_in[11];
    const float* ln2b  = (const float*)d_in[12];
    float* out = (float*)d_out;
    float* ws  = (float*)d_ws;

    // Workspace (floats):
    //   A  = [0, NTC)       : xs, then nrm (after LN1)
    //   B  = [NTC, 2NTC)    : qkv16 (fp16) -> res1 -> tmp2
    //   C  = [2NTC, ...)    : h16 (fp16), then W16 tail
    // ctx16 / res2 live in d_out.
    const int G = (ws_size >= (size_t)3 * NTC * sizeof(float)) ? 4 : 8;
    const int Ng = N_ / G;
    const long long Mg = (long long)Ng * T_;

    float* xs   = ws;
    float* nrm  = ws;
    _Float16* qkv16 = (_Float16*)(ws + NTC);
    float* res1 = ws + NTC;
    float* tmp2 = ws + NTC;
    _Float16* h16 = (_Float16*)(ws + 2 * NTC);
    float* wtail = ws + 2 * NTC + (size_t)Mg * 512;
    _Float16* w16_in  = (_Float16*)wtail;           // 196608
    _Float16* w16_out = w16_in + 196608;            // 65536
    _Float16* w16_1   = w16_out + 65536;            // 262144
    _Float16* w16_2   = w16_1 + 262144;             // 262144
    _Float16* ctx16 = (_Float16*)d_out;             // d_out as scratch (fp16)
    float* res2 = out;                              // d_out as scratch (fp32)

    // weight conversion
    k_cvt16<<<192, 256, 0, stream>>>(in_w,  w16_in,  196608 / 4);
    k_cvt16<<<64,  256, 0, stream>>>(out_w, w16_out, 65536 / 4);
    k_cvt16<<<256, 256, 0, stream>>>(w1,    w16_1,   262144 / 4);
    k_cvt16<<<256, 256, 0, stream>>>(w2,    w16_2,   262144 / 4);

    dim3 tb(32, 8);
    k_transpose_in<<<dim3(C_ / 32, F_ / 32, B_ * T_), tb, 0, stream>>>(x, xs);

    // QKV projection + attention, per sequence-group
    for (int g = 0; g < G; ++g) {
        const float* xs_g = xs + (size_t)g * Mg * C_;
        k_gemm_mfma<EPI_NONE, false, true><<<dim3(768 / 128, Mg / 128), 256, 0, stream>>>(
            xs_g, w16_in, in_b, nullptr, qkv16, 3 * C_, C_);
        k_attn_mfma<<<dim3(T_ / 64, Ng * H_), 256, 0, stream>>>(
            qkv16, ctx16 + (size_t)g * Mg * C_);
    }

    // out projection + residual(xs), full M (A = fp16 ctx)
    k_gemm_mfma<EPI_RES, true, false><<<dim3(C_ / 128, M_ / 128), 256, 0, stream>>>(
        ctx16, w16_out, out_b, xs, res1, C_, C_);

    // LN1: res1 -> nrm
    k_ln<<<M_ / 4, 256, 0, stream>>>(res1, ln1g, ln1b, nrm);

    // FFN per row-group
    for (int g = 0; g < G; ++g) {
        const float* nrm_g = nrm + (size_t)g * Mg * C_;
        k_gemm_mfma<EPI_GELU, false, true><<<dim3(FF / 128, Mg / 128), 256, 0, stream>>>(
            nrm_g, w16_1, b1, nullptr, h16, FF, C_);
        k_gemm_mfma<EPI_RES, true, false><<<dim3(C_ / 128, Mg / 128), 256, 0, stream>>>(
            h16, w16_2, b2, nrm_g, res2 + (size_t)g * Mg * C_, C_, FF);
    }

    // LN2: res2(d_out) -> tmp2
    k_ln<<<M_ / 4, 256, 0, stream>>>(res2, ln2g, ln2b, tmp2);

    // back to (B,C,T,F)
    k_transpose_out<<<dim3(C_ / 32, F_ / 32, B_ * T_), tb, 0, stream>>>(tmp2, out);
}